// Round 9
// baseline (240.552 us; speedup 1.0000x reference)
//
#include <hip/hip_runtime.h>

#define NN 100000
#define NE 600000
#define DIN 128
#define DOUT 64
#define SCAN_B 512
#define NBLK ((NN + SCAN_B - 1) / SCAN_B)  // 196
#define HIST_B ((NE + 255) / 256)          // 2344
#define G1_BM 128
#define G1B ((NN + G1_BM - 1) / G1_BM)     // 782  (gemm1 + spmm1_gemm2 grid)
#define ZB ((NN + 255) / 256)              // 391  (cnt zero blocks)
#define W1B (DIN * DIN / 256)              // 64
#define W2B (DIN * DOUT / 256)             // 32
#define XS_PITCH 136
#define RP_PITCH 144                        // byte pitch for epilogue repack (16-aligned)

typedef __attribute__((ext_vector_type(8))) short bf16x8;
typedef __attribute__((ext_vector_type(4))) short s16x4;
typedef __attribute__((ext_vector_type(4))) float f32x4;
typedef __attribute__((ext_vector_type(2))) float f32x2;

__device__ inline short f2bf(float f) {  // RTN-even fp32 -> bf16 bits
  union { float f; unsigned u; } v; v.f = f;
  unsigned r = (v.u + 0x7FFF + ((v.u >> 16) & 1)) >> 16;
  return (short)r;
}
__device__ inline float bf2f(unsigned short u) {
  union { unsigned u; float f; } v; v.u = ((unsigned)u) << 16;
  return v.f;
}
__device__ inline unsigned char f2fp8(float f) {  // HW e4m3 (OCP on gfx950)
  unsigned pk = __builtin_amdgcn_cvt_pk_fp8_f32(f, f, 0, false);
  return (unsigned char)(pk & 0xff);
}
// 16 fp8 bytes -> 16 f32 FMAs into acc[]
__device__ inline void fma_fp8x16(uint4 q, float w, float* acc) {
  f32x2 f;
  f = __builtin_amdgcn_cvt_pk_f32_fp8(q.x, false); acc[0] += w * f[0];  acc[1] += w * f[1];
  f = __builtin_amdgcn_cvt_pk_f32_fp8(q.x, true);  acc[2] += w * f[0];  acc[3] += w * f[1];
  f = __builtin_amdgcn_cvt_pk_f32_fp8(q.y, false); acc[4] += w * f[0];  acc[5] += w * f[1];
  f = __builtin_amdgcn_cvt_pk_f32_fp8(q.y, true);  acc[6] += w * f[0];  acc[7] += w * f[1];
  f = __builtin_amdgcn_cvt_pk_f32_fp8(q.z, false); acc[8] += w * f[0];  acc[9] += w * f[1];
  f = __builtin_amdgcn_cvt_pk_f32_fp8(q.z, true);  acc[10] += w * f[0]; acc[11] += w * f[1];
  f = __builtin_amdgcn_cvt_pk_f32_fp8(q.w, false); acc[12] += w * f[0]; acc[13] += w * f[1];
  f = __builtin_amdgcn_cvt_pk_f32_fp8(q.w, true);  acc[14] += w * f[0]; acc[15] += w * f[1];
}
// 8 bf16 (as uint4) -> 8 f32 FMAs into acc[]
__device__ inline void fma_bf16x8(uint4 q, float w, float* acc) {
  unsigned u;
  u = q.x; acc[0] += w * __uint_as_float(u << 16); acc[1] += w * __uint_as_float(u & 0xffff0000u);
  u = q.y; acc[2] += w * __uint_as_float(u << 16); acc[3] += w * __uint_as_float(u & 0xffff0000u);
  u = q.z; acc[4] += w * __uint_as_float(u << 16); acc[5] += w * __uint_as_float(u & 0xffff0000u);
  u = q.w; acc[6] += w * __uint_as_float(u << 16); acc[7] += w * __uint_as_float(u & 0xffff0000u);
}

// ---- prep: zero cnt + W1^T/W2^T bf16 (absorbs the memset) ----
__global__ __launch_bounds__(256) void prep_kernel(int* __restrict__ cnt,
                                                   const float* __restrict__ W1,
                                                   short* __restrict__ w1t,
                                                   const float* __restrict__ W2,
                                                   short* __restrict__ w2t) {
  const int b = blockIdx.x, t = threadIdx.x;
  if (b < ZB) {
    int i = b * 256 + t;
    if (i < NN) cnt[i] = 0;
  } else if (b < ZB + W1B) {
    int i = (b - ZB) * 256 + t;          // < 16384
    int n = i >> 7, k = i & 127;
    w1t[i] = f2bf(W1[k * DIN + n]);      // w1t[n][k]
  } else {
    int i = (b - ZB - W1B) * 256 + t;    // < 8192
    int n = i >> 7, k = i & 127;
    w2t[i] = f2bf(W2[k * DOUT + n]);     // w2t[n][k]
  }
}

// ---- standalone histogram: light regs, full occupancy ----
__global__ __launch_bounds__(256) void hist_kernel(const int* __restrict__ ei,
                                                   int* __restrict__ cnt,
                                                   int* __restrict__ rank) {
  int e = blockIdx.x * 256 + threadIdx.x;
  if (e < NE) rank[e] = atomicAdd(&cnt[ei[NE + e]], 1);  // rank = old count
}

__global__ __launch_bounds__(512) void scan_local_kernel(const int* __restrict__ cnt,
                                                         int* __restrict__ row_ptr,
                                                         int* __restrict__ blk_sum) {
  __shared__ int s[512];
  const int b = blockIdx.x, t = threadIdx.x;
  const int i = b * 512 + t;
  int v = (i < NN) ? cnt[i] : 0;
  s[t] = v;
  __syncthreads();
  for (int off = 1; off < 512; off <<= 1) {
    int u = (t >= off) ? s[t - off] : 0;
    __syncthreads();
    s[t] += u;
    __syncthreads();
  }
  if (i < NN) row_ptr[i] = s[t] - v;  // block-local exclusive
  if (t == 511) blk_sum[b] = s[511];
}

__global__ __launch_bounds__(512) void scan_add_kernel(int* __restrict__ row_ptr,
                                                       const int* __restrict__ blk_sum) {
  __shared__ int s[512];
  const int b = blockIdx.x, t = threadIdx.x;
  s[t] = (t < NBLK) ? blk_sum[t] : 0;
  __syncthreads();
  for (int off = 1; off < 512; off <<= 1) {
    int u = (t >= off) ? s[t - off] : 0;
    __syncthreads();
    s[t] += u;
    __syncthreads();
  }
  int off = (b > 0) ? s[b - 1] : 0;  // inclusive scan -> exclusive block offset
  const int i = b * 512 + t;
  if (i < NN) row_ptr[i] += off;
  if (b == 0 && t == 0) row_ptr[NN] = NE;
}

// atomic-free scatter: pos = row_ptr[dst] + rank[e]
__global__ __launch_bounds__(256) void scatter_kernel(const int* __restrict__ ei,
                                                      const float* __restrict__ ew,
                                                      const int* __restrict__ row_ptr,
                                                      const int* __restrict__ rank,
                                                      int2* __restrict__ ep) {
  int e = blockIdx.x * 256 + threadIdx.x;
  if (e >= NE) return;
  int src = ei[e];
  int dst = ei[NE + e];
  int pos = row_ptr[dst] + rank[e];
  ep[pos] = make_int2(src, __float_as_int(ew[e]));
}

// ---- GEMM1: h0(fp8) = x @ W1 ; BM=128, 8 waves x 16 rows, coalesced epilogue ----
__global__ __launch_bounds__(512) void gemm1_kernel(const float* __restrict__ x,
                                                    const short* __restrict__ w1t,
                                                    unsigned char* __restrict__ h0) {
  __shared__ short xs[G1_BM][XS_PITCH];   // reused as byte buf in epilogue
  const int t = threadIdx.x;
  const int row0 = blockIdx.x * G1_BM;
#pragma unroll
  for (int i = 0; i < 8; ++i) {
    int f = t + i * 512;
    int r = f >> 5, c4 = f & 31;
    int gr = row0 + r;
    float4 v = (gr < NN) ? *(const float4*)&x[(size_t)gr * DIN + c4 * 4]
                         : make_float4(0.f, 0.f, 0.f, 0.f);
    s16x4 s;
    s.x = f2bf(v.x); s.y = f2bf(v.y); s.z = f2bf(v.z); s.w = f2bf(v.w);
    *(s16x4*)&xs[r][c4 * 4] = s;
  }
  __syncthreads();

  const int wave = t >> 6, lane = t & 63;
  const int nlane = lane & 15, quad = lane >> 4;
  const int mbase = wave * 16;
  f32x4 acc[8];
#pragma unroll
  for (int nt = 0; nt < 8; ++nt) acc[nt] = (f32x4){0.f, 0.f, 0.f, 0.f};

#pragma unroll
  for (int ks = 0; ks < 4; ++ks) {
    const int koff = ks * 32 + quad * 8;
    bf16x8 a = *(const bf16x8*)&xs[mbase + nlane][koff];
#pragma unroll
    for (int nt = 0; nt < 8; ++nt) {
      bf16x8 b = *(const bf16x8*)&w1t[(size_t)(nt * 16 + nlane) * DIN + koff];
      acc[nt] = __builtin_amdgcn_mfma_f32_16x16x32_bf16(a, b, acc[nt], 0, 0, 0);
    }
  }

  // epilogue: fp8 bytes -> LDS repack -> 32 B contiguous per thread
  __syncthreads();  // xs A-data dead
  unsigned char* lsb = (unsigned char*)xs;  // [128][RP_PITCH] bytes
#pragma unroll
  for (int nt = 0; nt < 8; ++nt)
#pragma unroll
    for (int rg = 0; rg < 4; ++rg)
      lsb[(mbase + quad * 4 + rg) * RP_PITCH + nt * 16 + nlane] = f2fp8(acc[nt][rg]);
  __syncthreads();
  {
    const int r = t >> 2, q = t & 3;
    const int gr = row0 + r;
    if (gr < NN) {
      const uint4* s = (const uint4*)(lsb + r * RP_PITCH + q * 32);
      uint4* d = (uint4*)&h0[(size_t)gr * DIN + q * 32];
      d[0] = s[0]; d[1] = s[1];
    }
  }
}

// ---- fused spmm1 + gemm2: block owns 128 rows; unroll-8 predicated gather ----
// phase A: 512 threads = 64 rows x 8 lanes, 2 batches; relu(acc+b1) -> xs bf16
// phase B: 8 waves x 16 rows MFMA tile, h2 = xs @ W2; coalesced epilogue
__global__ __launch_bounds__(512) void spmm1_gemm2_kernel(const int* __restrict__ rp,
                                                          const int2* __restrict__ ep,
                                                          const unsigned char* __restrict__ h,
                                                          const float* __restrict__ b1,
                                                          const short* __restrict__ w2t,
                                                          short* __restrict__ h2) {
  __shared__ short xs[G1_BM][XS_PITCH];
  const int t = threadIdx.x;
  const int row0 = blockIdx.x * G1_BM;
  const int sub = t >> 3, lane8 = t & 7;  // lane8 owns bytes [lane8*16, +16)
  float bb[16];
  *(float4*)&bb[0]  = *(const float4*)&b1[lane8 * 16];
  *(float4*)&bb[4]  = *(const float4*)&b1[lane8 * 16 + 4];
  *(float4*)&bb[8]  = *(const float4*)&b1[lane8 * 16 + 8];
  *(float4*)&bb[12] = *(const float4*)&b1[lane8 * 16 + 12];

#pragma unroll
  for (int batch = 0; batch < 2; ++batch) {
    const int r = batch * 64 + sub;
    const int row = row0 + r;
    float acc[16];
#pragma unroll
    for (int j = 0; j < 16; ++j) acc[j] = 0.f;
    if (row < NN) {
      const int b0 = rp[row], e1 = rp[row + 1];
      // unroll-8 predicated gather: 8 independent 16 B loads in flight
      for (int i = b0; i < e1; i += 8) {
        int2 p[8];
        uint4 q[8];
#pragma unroll
        for (int k = 0; k < 8; ++k)
          if (i + k < e1) p[k] = ep[i + k];
#pragma unroll
        for (int k = 0; k < 8; ++k)
          if (i + k < e1) q[k] = *(const uint4*)&h[(size_t)p[k].x * DIN + lane8 * 16];
#pragma unroll
        for (int k = 0; k < 8; ++k)
          if (i + k < e1) fma_fp8x16(q[k], __int_as_float(p[k].y), acc);
      }
    }
    bf16x8 o0, o1;
#pragma unroll
    for (int j = 0; j < 8; ++j) {
      o0[j] = f2bf(fmaxf(acc[j] + bb[j], 0.f));
      o1[j] = f2bf(fmaxf(acc[8 + j] + bb[8 + j], 0.f));
    }
    *(bf16x8*)&xs[r][lane8 * 16] = o0;
    *(bf16x8*)&xs[r][lane8 * 16 + 8] = o1;
  }
  __syncthreads();

  // phase B: h2 = xs @ W2 (8 waves, 16 rows each)
  const int wave = t >> 6, lane = t & 63;
  const int nlane = lane & 15, quad = lane >> 4;
  const int mbase = wave * 16;
  f32x4 acc2[4];
#pragma unroll
  for (int nt = 0; nt < 4; ++nt) acc2[nt] = (f32x4){0.f, 0.f, 0.f, 0.f};
#pragma unroll
  for (int ks = 0; ks < 4; ++ks) {
    const int koff = ks * 32 + quad * 8;
    bf16x8 a0 = *(const bf16x8*)&xs[mbase + nlane][koff];
#pragma unroll
    for (int nt = 0; nt < 4; ++nt) {
      bf16x8 bfr = *(const bf16x8*)&w2t[(size_t)(nt * 16 + nlane) * DIN + koff];
      acc2[nt] = __builtin_amdgcn_mfma_f32_16x16x32_bf16(a0, bfr, acc2[nt], 0, 0, 0);
    }
  }

  // epilogue: bf16 -> LDS repack -> 32 B contiguous per thread
  __syncthreads();  // xs dead
  unsigned char* lsb = (unsigned char*)xs;  // [128][RP_PITCH] bytes
#pragma unroll
  for (int nt = 0; nt < 4; ++nt)
#pragma unroll
    for (int rg = 0; rg < 4; ++rg)
      *(short*)(lsb + (mbase + quad * 4 + rg) * RP_PITCH + (nt * 16 + nlane) * 2) =
          f2bf(acc2[nt][rg]);
  __syncthreads();
  {
    const int r = t >> 2, q = t & 3;
    const int gr = row0 + r;
    if (gr < NN) {
      const uint4* s = (const uint4*)(lsb + r * RP_PITCH + q * 32);
      uint4* d = (uint4*)&h2[(size_t)gr * DOUT + q * 16];
      d[0] = s[0]; d[1] = s[1];
    }
  }
}

// ------- spmm2: out(fp32) = A @ h2(bf16) + b2; unroll-8 predicated gather ----
__global__ __launch_bounds__(256) void spmm2_kernel(const int* __restrict__ rp,
                                                    const int2* __restrict__ ep,
                                                    const short* __restrict__ h,
                                                    const float* __restrict__ bias,
                                                    float* __restrict__ out) {
  const int row = blockIdx.x * 32 + (threadIdx.x >> 3);
  const int lane = threadIdx.x & 7;  // owns elems [lane*8, lane*8+8)
  if (row >= NN) return;
  const int b = rp[row], e = rp[row + 1];
  float acc[8];
#pragma unroll
  for (int j = 0; j < 8; ++j) acc[j] = 0.f;
  for (int i = b; i < e; i += 8) {
    int2 p[8];
    uint4 q[8];
#pragma unroll
    for (int k = 0; k < 8; ++k)
      if (i + k < e) p[k] = ep[i + k];
#pragma unroll
    for (int k = 0; k < 8; ++k)
      if (i + k < e) q[k] = *(const uint4*)&h[(size_t)p[k].x * DOUT + lane * 8];
#pragma unroll
    for (int k = 0; k < 8; ++k)
      if (i + k < e) fma_bf16x8(q[k], __int_as_float(p[k].y), acc);
  }
#pragma unroll
  for (int j = 0; j < 8; ++j) acc[j] += bias[lane * 8 + j];
  *(float4*)&out[(size_t)row * DOUT + lane * 8] = make_float4(acc[0], acc[1], acc[2], acc[3]);
  *(float4*)&out[(size_t)row * DOUT + lane * 8 + 4] = make_float4(acc[4], acc[5], acc[6], acc[7]);
}

extern "C" void kernel_launch(void* const* d_in, const int* in_sizes, int n_in,
                              void* d_out, int out_size, void* d_ws, size_t ws_size,
                              hipStream_t stream) {
  const float* x  = (const float*)d_in[0];
  const int*   ei = (const int*)d_in[1];
  const float* ew = (const float*)d_in[2];
  const float* W1 = (const float*)d_in[3];
  const float* b1 = (const float*)d_in[4];
  const float* W2 = (const float*)d_in[5];
  const float* b2 = (const float*)d_in[6];
  float* out = (float*)d_out;

  // workspace layout — ~33.7 MB (82.4 MB proven safe)
  char* p = (char*)d_ws;
  int*   cnt     = (int*)p;                 p += sizeof(int) * NN;
  int*   row_ptr = (int*)p;                 p += sizeof(int) * (NN + 4);
  int*   blk_sum = (int*)p;                 p += sizeof(int) * (NBLK + 4);
  int*   rank    = (int*)p;                 p += sizeof(int) * NE;
  int2*  ep      = (int2*)p;                p += sizeof(int2) * NE;      // (src, w)
  short* w1t     = (short*)p;               p += sizeof(short) * DIN * DIN;
  short* w2t     = (short*)p;               p += sizeof(short) * DIN * DOUT;
  unsigned char* h0 = (unsigned char*)p;    p += (size_t)NN * DIN;      // fp8 e4m3
  short* h2      = (short*)p;               // [NN, DOUT] bf16

  // prep (zero cnt + weight transposes)
  prep_kernel<<<ZB + W1B + W2B, 256, 0, stream>>>(cnt, W1, w1t, W2, w2t);
  // CSR build
  hist_kernel<<<HIST_B, 256, 0, stream>>>(ei, cnt, rank);
  scan_local_kernel<<<NBLK, 512, 0, stream>>>(cnt, row_ptr, blk_sum);
  scan_add_kernel<<<NBLK, 512, 0, stream>>>(row_ptr, blk_sum);
  scatter_kernel<<<HIST_B, 256, 0, stream>>>(ei, ew, row_ptr, rank, ep);
  // layer 1 dense (BM=128, 8 waves, coalesced epilogue)
  gemm1_kernel<<<G1B, 512, 0, stream>>>(x, w1t, h0);
  // layer 1 spmm + layer 2 gemm fused (acc1 never touches HBM)
  spmm1_gemm2_kernel<<<G1B, 512, 0, stream>>>(row_ptr, ep, h0, b1, w2t, h2);
  spmm2_kernel<<<(NN + 31) / 32, 256, 0, stream>>>(row_ptr, ep, h2, b2, out);
}

// Round 10
// 224.242 us; speedup vs baseline: 1.0727x; 1.0727x over previous
//
#include <hip/hip_runtime.h>

#define NN 100000
#define NE 600000
#define DIN 128
#define DOUT 64
#define SCAN_B 512
#define NBLK ((NN + SCAN_B - 1) / SCAN_B)  // 196
#define HIST_B ((NE + 255) / 256)          // 2344
#define G1_BM 128
#define G1B ((NN + G1_BM - 1) / G1_BM)     // 782  (gemm1 + spmm1_gemm2 grid)
#define ZB ((NN + 255) / 256)              // 391  (cnt zero blocks)
#define W1B (DIN * DIN / 256)              // 64
#define W2B (DIN * DOUT / 256)             // 32
#define XS_PITCH 136
#define RP_PITCH 144                        // byte pitch for epilogue repack (16-aligned)

typedef __attribute__((ext_vector_type(8))) short bf16x8;
typedef __attribute__((ext_vector_type(4))) short s16x4;
typedef __attribute__((ext_vector_type(4))) float f32x4;
typedef __attribute__((ext_vector_type(2))) float f32x2;

__device__ inline short f2bf(float f) {  // RTN-even fp32 -> bf16 bits
  union { float f; unsigned u; } v; v.f = f;
  unsigned r = (v.u + 0x7FFF + ((v.u >> 16) & 1)) >> 16;
  return (short)r;
}
__device__ inline float bf2f(unsigned short u) {
  union { unsigned u; float f; } v; v.u = ((unsigned)u) << 16;
  return v.f;
}
__device__ inline unsigned char f2fp8(float f) {  // HW e4m3 (OCP on gfx950)
  unsigned pk = __builtin_amdgcn_cvt_pk_fp8_f32(f, f, 0, false);
  return (unsigned char)(pk & 0xff);
}
// 16 fp8 bytes -> 16 f32 FMAs into acc[]
__device__ inline void fma_fp8x16(uint4 q, float w, float* acc) {
  f32x2 f;
  f = __builtin_amdgcn_cvt_pk_f32_fp8(q.x, false); acc[0] += w * f[0];  acc[1] += w * f[1];
  f = __builtin_amdgcn_cvt_pk_f32_fp8(q.x, true);  acc[2] += w * f[0];  acc[3] += w * f[1];
  f = __builtin_amdgcn_cvt_pk_f32_fp8(q.y, false); acc[4] += w * f[0];  acc[5] += w * f[1];
  f = __builtin_amdgcn_cvt_pk_f32_fp8(q.y, true);  acc[6] += w * f[0];  acc[7] += w * f[1];
  f = __builtin_amdgcn_cvt_pk_f32_fp8(q.z, false); acc[8] += w * f[0];  acc[9] += w * f[1];
  f = __builtin_amdgcn_cvt_pk_f32_fp8(q.z, true);  acc[10] += w * f[0]; acc[11] += w * f[1];
  f = __builtin_amdgcn_cvt_pk_f32_fp8(q.w, false); acc[12] += w * f[0]; acc[13] += w * f[1];
  f = __builtin_amdgcn_cvt_pk_f32_fp8(q.w, true);  acc[14] += w * f[0]; acc[15] += w * f[1];
}
// 8 bf16 (as uint4) -> 8 f32 FMAs into acc[]
__device__ inline void fma_bf16x8(uint4 q, float w, float* acc) {
  unsigned u;
  u = q.x; acc[0] += w * __uint_as_float(u << 16); acc[1] += w * __uint_as_float(u & 0xffff0000u);
  u = q.y; acc[2] += w * __uint_as_float(u << 16); acc[3] += w * __uint_as_float(u & 0xffff0000u);
  u = q.z; acc[4] += w * __uint_as_float(u << 16); acc[5] += w * __uint_as_float(u & 0xffff0000u);
  u = q.w; acc[6] += w * __uint_as_float(u << 16); acc[7] += w * __uint_as_float(u & 0xffff0000u);
}

// ---- prep: zero cnt + W1^T/W2^T bf16 (absorbs the memset) ----
__global__ __launch_bounds__(256) void prep_kernel(int* __restrict__ cnt,
                                                   const float* __restrict__ W1,
                                                   short* __restrict__ w1t,
                                                   const float* __restrict__ W2,
                                                   short* __restrict__ w2t) {
  const int b = blockIdx.x, t = threadIdx.x;
  if (b < ZB) {
    int i = b * 256 + t;
    if (i < NN) cnt[i] = 0;
  } else if (b < ZB + W1B) {
    int i = (b - ZB) * 256 + t;          // < 16384
    int n = i >> 7, k = i & 127;
    w1t[i] = f2bf(W1[k * DIN + n]);      // w1t[n][k]
  } else {
    int i = (b - ZB - W1B) * 256 + t;    // < 8192
    int n = i >> 7, k = i & 127;
    w2t[i] = f2bf(W2[k * DOUT + n]);     // w2t[n][k]
  }
}

// ---- standalone histogram: light regs, full occupancy ----
__global__ __launch_bounds__(256) void hist_kernel(const int* __restrict__ ei,
                                                   int* __restrict__ cnt,
                                                   int* __restrict__ rank) {
  int e = blockIdx.x * 256 + threadIdx.x;
  if (e < NE) rank[e] = atomicAdd(&cnt[ei[NE + e]], 1);  // rank = old count
}

__global__ __launch_bounds__(512) void scan_local_kernel(const int* __restrict__ cnt,
                                                         int* __restrict__ row_ptr,
                                                         int* __restrict__ blk_sum) {
  __shared__ int s[512];
  const int b = blockIdx.x, t = threadIdx.x;
  const int i = b * 512 + t;
  int v = (i < NN) ? cnt[i] : 0;
  s[t] = v;
  __syncthreads();
  for (int off = 1; off < 512; off <<= 1) {
    int u = (t >= off) ? s[t - off] : 0;
    __syncthreads();
    s[t] += u;
    __syncthreads();
  }
  if (i < NN) row_ptr[i] = s[t] - v;  // block-local exclusive
  if (t == 511) blk_sum[b] = s[511];
}

__global__ __launch_bounds__(512) void scan_add_kernel(int* __restrict__ row_ptr,
                                                       const int* __restrict__ blk_sum) {
  __shared__ int s[512];
  const int b = blockIdx.x, t = threadIdx.x;
  s[t] = (t < NBLK) ? blk_sum[t] : 0;
  __syncthreads();
  for (int off = 1; off < 512; off <<= 1) {
    int u = (t >= off) ? s[t - off] : 0;
    __syncthreads();
    s[t] += u;
    __syncthreads();
  }
  int off = (b > 0) ? s[b - 1] : 0;  // inclusive scan -> exclusive block offset
  const int i = b * 512 + t;
  if (i < NN) row_ptr[i] += off;
  if (b == 0 && t == 0) row_ptr[NN] = NE;
}

// atomic-free scatter: pos = row_ptr[dst] + rank[e]
__global__ __launch_bounds__(256) void scatter_kernel(const int* __restrict__ ei,
                                                      const float* __restrict__ ew,
                                                      const int* __restrict__ row_ptr,
                                                      const int* __restrict__ rank,
                                                      int2* __restrict__ ep) {
  int e = blockIdx.x * 256 + threadIdx.x;
  if (e >= NE) return;
  int src = ei[e];
  int dst = ei[NE + e];
  int pos = row_ptr[dst] + rank[e];
  ep[pos] = make_int2(src, __float_as_int(ew[e]));
}

// ---- GEMM1: h0(fp8) = x @ W1 ; BM=128, 4 waves x 32 rows ----
// W1^T staged in LDS (32 KB, pitch-padded): B-frags come from LDS (~12 cy)
// instead of 128 KB/block of global/L2 traffic. Coalesced LDS-repack epilogue.
__global__ __launch_bounds__(256) void gemm1_kernel(const float* __restrict__ x,
                                                    const short* __restrict__ w1t,
                                                    unsigned char* __restrict__ h0) {
  __shared__ short xs[G1_BM][XS_PITCH];   // reused as byte buf in epilogue
  __shared__ short w1s[DIN][XS_PITCH];    // pitch 136: rows 4 banks apart -> 2-way max
  const int t = threadIdx.x;
  const int row0 = blockIdx.x * G1_BM;
#pragma unroll
  for (int i = 0; i < 16; ++i) {
    int f = t + i * 256;
    int r = f >> 5, c4 = f & 31;
    int gr = row0 + r;
    float4 v = (gr < NN) ? *(const float4*)&x[(size_t)gr * DIN + c4 * 4]
                         : make_float4(0.f, 0.f, 0.f, 0.f);
    s16x4 s;
    s.x = f2bf(v.x); s.y = f2bf(v.y); s.z = f2bf(v.z); s.w = f2bf(v.w);
    *(s16x4*)&xs[r][c4 * 4] = s;
  }
  // stage w1t -> LDS (coalesced b128 copies, 8 per thread)
#pragma unroll
  for (int i = 0; i < 8; ++i) {
    int f = t + i * 256;                 // f < 2048
    int n = f >> 4, k8 = f & 15;
    *(bf16x8*)&w1s[n][k8 * 8] = *(const bf16x8*)&w1t[n * DIN + k8 * 8];
  }
  __syncthreads();

  const int wave = t >> 6, lane = t & 63;
  const int nlane = lane & 15, quad = lane >> 4;
  const int mbase = wave * 32;
  f32x4 acc[2][8];
#pragma unroll
  for (int mt = 0; mt < 2; ++mt)
#pragma unroll
    for (int nt = 0; nt < 8; ++nt) acc[mt][nt] = (f32x4){0.f, 0.f, 0.f, 0.f};

#pragma unroll
  for (int ks = 0; ks < 4; ++ks) {
    const int koff = ks * 32 + quad * 8;
    bf16x8 a0 = *(const bf16x8*)&xs[mbase + nlane][koff];
    bf16x8 a1 = *(const bf16x8*)&xs[mbase + 16 + nlane][koff];
#pragma unroll
    for (int nt = 0; nt < 8; ++nt) {
      bf16x8 b = *(const bf16x8*)&w1s[nt * 16 + nlane][koff];
      acc[0][nt] = __builtin_amdgcn_mfma_f32_16x16x32_bf16(a0, b, acc[0][nt], 0, 0, 0);
      acc[1][nt] = __builtin_amdgcn_mfma_f32_16x16x32_bf16(a1, b, acc[1][nt], 0, 0, 0);
    }
  }

  // epilogue: fp8 bytes -> LDS repack -> 64 B contiguous per thread
  __syncthreads();  // xs A-data dead
  unsigned char* lsb = (unsigned char*)xs;  // [128][RP_PITCH] bytes
#pragma unroll
  for (int mt = 0; mt < 2; ++mt)
#pragma unroll
    for (int nt = 0; nt < 8; ++nt)
#pragma unroll
      for (int rg = 0; rg < 4; ++rg)
        lsb[(mbase + mt * 16 + quad * 4 + rg) * RP_PITCH + nt * 16 + nlane] =
            f2fp8(acc[mt][nt][rg]);
  __syncthreads();
  {
    const int r = t >> 1, half = t & 1;
    const int gr = row0 + r;
    if (gr < NN) {
      const uint4* s = (const uint4*)(lsb + r * RP_PITCH + half * 64);
      uint4* d = (uint4*)&h0[(size_t)gr * DIN + half * 64];
      d[0] = s[0]; d[1] = s[1]; d[2] = s[2]; d[3] = s[3];
    }
  }
}

// ---- fused spmm1 + gemm2: block owns 128 rows; unroll-8 predicated gather ----
// phase A: 512 threads = 64 rows x 8 lanes, 2 batches; relu(acc+b1) -> xs bf16
// phase B: 8 waves x 16 rows MFMA tile, h2 = xs @ W2; coalesced epilogue
__global__ __launch_bounds__(512) void spmm1_gemm2_kernel(const int* __restrict__ rp,
                                                          const int2* __restrict__ ep,
                                                          const unsigned char* __restrict__ h,
                                                          const float* __restrict__ b1,
                                                          const short* __restrict__ w2t,
                                                          short* __restrict__ h2) {
  __shared__ short xs[G1_BM][XS_PITCH];
  const int t = threadIdx.x;
  const int row0 = blockIdx.x * G1_BM;
  const int sub = t >> 3, lane8 = t & 7;  // lane8 owns bytes [lane8*16, +16)
  float bb[16];
  *(float4*)&bb[0]  = *(const float4*)&b1[lane8 * 16];
  *(float4*)&bb[4]  = *(const float4*)&b1[lane8 * 16 + 4];
  *(float4*)&bb[8]  = *(const float4*)&b1[lane8 * 16 + 8];
  *(float4*)&bb[12] = *(const float4*)&b1[lane8 * 16 + 12];

#pragma unroll
  for (int batch = 0; batch < 2; ++batch) {
    const int r = batch * 64 + sub;
    const int row = row0 + r;
    float acc[16];
#pragma unroll
    for (int j = 0; j < 16; ++j) acc[j] = 0.f;
    if (row < NN) {
      const int b0 = rp[row], e1 = rp[row + 1];
      // unroll-8 predicated gather: 8 independent 16 B loads in flight
      for (int i = b0; i < e1; i += 8) {
        int2 p[8];
        uint4 q[8];
#pragma unroll
        for (int k = 0; k < 8; ++k)
          if (i + k < e1) p[k] = ep[i + k];
#pragma unroll
        for (int k = 0; k < 8; ++k)
          if (i + k < e1) q[k] = *(const uint4*)&h[(size_t)p[k].x * DIN + lane8 * 16];
#pragma unroll
        for (int k = 0; k < 8; ++k)
          if (i + k < e1) fma_fp8x16(q[k], __int_as_float(p[k].y), acc);
      }
    }
    bf16x8 o0, o1;
#pragma unroll
    for (int j = 0; j < 8; ++j) {
      o0[j] = f2bf(fmaxf(acc[j] + bb[j], 0.f));
      o1[j] = f2bf(fmaxf(acc[8 + j] + bb[8 + j], 0.f));
    }
    *(bf16x8*)&xs[r][lane8 * 16] = o0;
    *(bf16x8*)&xs[r][lane8 * 16 + 8] = o1;
  }
  __syncthreads();

  // phase B: h2 = xs @ W2 (8 waves, 16 rows each)
  const int wave = t >> 6, lane = t & 63;
  const int nlane = lane & 15, quad = lane >> 4;
  const int mbase = wave * 16;
  f32x4 acc2[4];
#pragma unroll
  for (int nt = 0; nt < 4; ++nt) acc2[nt] = (f32x4){0.f, 0.f, 0.f, 0.f};
#pragma unroll
  for (int ks = 0; ks < 4; ++ks) {
    const int koff = ks * 32 + quad * 8;
    bf16x8 a0 = *(const bf16x8*)&xs[mbase + nlane][koff];
#pragma unroll
    for (int nt = 0; nt < 4; ++nt) {
      bf16x8 bfr = *(const bf16x8*)&w2t[(size_t)(nt * 16 + nlane) * DIN + koff];
      acc2[nt] = __builtin_amdgcn_mfma_f32_16x16x32_bf16(a0, bfr, acc2[nt], 0, 0, 0);
    }
  }

  // epilogue: bf16 -> LDS repack -> 32 B contiguous per thread
  __syncthreads();  // xs dead
  unsigned char* lsb = (unsigned char*)xs;  // [128][RP_PITCH] bytes
#pragma unroll
  for (int nt = 0; nt < 4; ++nt)
#pragma unroll
    for (int rg = 0; rg < 4; ++rg)
      *(short*)(lsb + (mbase + quad * 4 + rg) * RP_PITCH + (nt * 16 + nlane) * 2) =
          f2bf(acc2[nt][rg]);
  __syncthreads();
  {
    const int r = t >> 2, q = t & 3;
    const int gr = row0 + r;
    if (gr < NN) {
      const uint4* s = (const uint4*)(lsb + r * RP_PITCH + q * 32);
      uint4* d = (uint4*)&h2[(size_t)gr * DOUT + q * 16];
      d[0] = s[0]; d[1] = s[1];
    }
  }
}

// ------- spmm2: out(fp32) = A @ h2(bf16) + b2; unroll-8 predicated gather ----
__global__ __launch_bounds__(256) void spmm2_kernel(const int* __restrict__ rp,
                                                    const int2* __restrict__ ep,
                                                    const short* __restrict__ h,
                                                    const float* __restrict__ bias,
                                                    float* __restrict__ out) {
  const int row = blockIdx.x * 32 + (threadIdx.x >> 3);
  const int lane = threadIdx.x & 7;  // owns elems [lane*8, lane*8+8)
  if (row >= NN) return;
  const int b = rp[row], e = rp[row + 1];
  float acc[8];
#pragma unroll
  for (int j = 0; j < 8; ++j) acc[j] = 0.f;
  for (int i = b; i < e; i += 8) {
    int2 p[8];
    uint4 q[8];
#pragma unroll
    for (int k = 0; k < 8; ++k)
      if (i + k < e) p[k] = ep[i + k];
#pragma unroll
    for (int k = 0; k < 8; ++k)
      if (i + k < e) q[k] = *(const uint4*)&h[(size_t)p[k].x * DOUT + lane * 8];
#pragma unroll
    for (int k = 0; k < 8; ++k)
      if (i + k < e) fma_bf16x8(q[k], __int_as_float(p[k].y), acc);
  }
#pragma unroll
  for (int j = 0; j < 8; ++j) acc[j] += bias[lane * 8 + j];
  *(float4*)&out[(size_t)row * DOUT + lane * 8] = make_float4(acc[0], acc[1], acc[2], acc[3]);
  *(float4*)&out[(size_t)row * DOUT + lane * 8 + 4] = make_float4(acc[4], acc[5], acc[6], acc[7]);
}

extern "C" void kernel_launch(void* const* d_in, const int* in_sizes, int n_in,
                              void* d_out, int out_size, void* d_ws, size_t ws_size,
                              hipStream_t stream) {
  const float* x  = (const float*)d_in[0];
  const int*   ei = (const int*)d_in[1];
  const float* ew = (const float*)d_in[2];
  const float* W1 = (const float*)d_in[3];
  const float* b1 = (const float*)d_in[4];
  const float* W2 = (const float*)d_in[5];
  const float* b2 = (const float*)d_in[6];
  float* out = (float*)d_out;

  // workspace layout — ~33.7 MB (82.4 MB proven safe)
  char* p = (char*)d_ws;
  int*   cnt     = (int*)p;                 p += sizeof(int) * NN;
  int*   row_ptr = (int*)p;                 p += sizeof(int) * (NN + 4);
  int*   blk_sum = (int*)p;                 p += sizeof(int) * (NBLK + 4);
  int*   rank    = (int*)p;                 p += sizeof(int) * NE;
  int2*  ep      = (int2*)p;                p += sizeof(int2) * NE;      // (src, w)
  short* w1t     = (short*)p;               p += sizeof(short) * DIN * DIN;
  short* w2t     = (short*)p;               p += sizeof(short) * DIN * DOUT;
  unsigned char* h0 = (unsigned char*)p;    p += (size_t)NN * DIN;      // fp8 e4m3
  short* h2      = (short*)p;               // [NN, DOUT] bf16

  // prep (zero cnt + weight transposes)
  prep_kernel<<<ZB + W1B + W2B, 256, 0, stream>>>(cnt, W1, w1t, W2, w2t);
  // CSR build
  hist_kernel<<<HIST_B, 256, 0, stream>>>(ei, cnt, rank);
  scan_local_kernel<<<NBLK, 512, 0, stream>>>(cnt, row_ptr, blk_sum);
  scan_add_kernel<<<NBLK, 512, 0, stream>>>(row_ptr, blk_sum);
  scatter_kernel<<<HIST_B, 256, 0, stream>>>(ei, ew, row_ptr, rank, ep);
  // layer 1 dense (BM=128, W1 in LDS, coalesced epilogue)
  gemm1_kernel<<<G1B, 256, 0, stream>>>(x, w1t, h0);
  // layer 1 spmm + layer 2 gemm fused (acc1 never touches HBM)
  spmm1_gemm2_kernel<<<G1B, 512, 0, stream>>>(row_ptr, ep, h0, b1, w2t, h2);
  spmm2_kernel<<<(NN + 31) / 32, 256, 0, stream>>>(row_ptr, ep, h2, b2, out);
}